// Round 1
// 1864.552 us; speedup vs baseline: 1.5699x; 1.5699x over previous
//
#include <hip/hip_runtime.h>
#include <cstdint>

using u16 = unsigned short;
using ull = unsigned long long;
typedef __bf16 bf16x8 __attribute__((ext_vector_type(8)));
typedef float  f32x4  __attribute__((ext_vector_type(4)));
typedef float  f32x16 __attribute__((ext_vector_type(16)));

#define DEV __device__ __forceinline__

// ---------- constants ----------
// B=32, T=128, V=32000, E=300(->320), H=512, 4H=2048, M=B*T=4096
static constexpr size_t OFF_XZ    = 0;                       // 4096*2048*4   = 33554432
static constexpr size_t OFF_AEMB  = 33554432;                // 4096*320*2    = 2621440
static constexpr size_t OFF_WXT   = 36175872;                // 2048*320*2    = 1310720
static constexpr size_t OFF_WOT   = 37486592;                // 32000*512*2   = 32768000
static constexpr size_t OFF_WHHI  = 70254592;                // 64*32*64*8*2  = 2097152
static constexpr size_t OFF_WHLO  = 72351744;                // 2097152
static constexpr size_t OFF_HS    = 74448896;                // 4096*512*2    = 4194304
static constexpr size_t OFF_HXHI  = 78643200;                // 2 slots * 32*512*2 = 65536
static constexpr size_t OFF_HXLO  = 78708736;                // 65536
static constexpr size_t OFF_BAR   = 78774272;                // 256 bytes

// ---------- helpers ----------
DEV u16 f2bf(float x) {                       // round-to-nearest-even fp32 -> bf16 bits
  union { float f; uint32_t u; } v; v.f = x;
  uint32_t r = v.u + 0x7fffu + ((v.u >> 16) & 1u);
  return (u16)(r >> 16);
}
DEV float bf2f(u16 h) { union { uint32_t u; float f; } v; v.u = ((uint32_t)h) << 16; return v.f; }
DEV float sigf(float x)  { return 1.f / (1.f + __expf(-x)); }
DEV float tanh_(float x) { return 2.f / (1.f + __expf(-2.f * x)) - 1.f; }

DEV f32x4 mfma16(bf16x8 a, bf16x8 b, f32x4 c) {
  return __builtin_amdgcn_mfma_f32_16x16x32_bf16(a, b, c, 0, 0, 0);
}
DEV f32x16 mfma32(bf16x8 a, bf16x8 b, f32x16 c) {
  return __builtin_amdgcn_mfma_f32_32x32x16_bf16(a, b, c, 0, 0, 0);
}
DEV void gl_lds16(const u16* g, u16* l) {     // async global->LDS, 16B/lane, dest = base + lane*16
  __builtin_amdgcn_global_load_lds(
      (const __attribute__((address_space(1))) uint32_t*)g,
      (__attribute__((address_space(3))) uint32_t*)l, 16, 0, 0);
}

// Fragment-order position of h element (b, k) within a 16384-u16 slot:
//   chunk16B = (k>>4)*64 + b*2 + ((k>>3)&1), elem j = k&7
// MFMA A-frag read for lane: chunk = s*64 + (lane&31)*2 + (lane>>5) -> 64 consecutive
// 16B chunks per wave-read = conflict-free ds_read_b128.

// ---------- prep kernels ----------
__global__ __launch_bounds__(256) void prep_aemb(const int* __restrict__ toks,
                                                 const float* __restrict__ emb,
                                                 u16* __restrict__ A) {
  int m = blockIdx.x;                          // row = b*T + t
  int tok = toks[m];
  const float* src = emb + (size_t)tok * 300;
  for (int k = threadIdx.x; k < 320; k += 256)
    A[(size_t)m * 320 + k] = (k < 300) ? f2bf(src[k]) : (u16)0;
}

// out[n][k] = (bf16) in[k][n];  K rows in, Kp (padded, %64) cols out, N %64
__global__ __launch_bounds__(256) void transpose_cvt(const float* __restrict__ in,
                                                     u16* __restrict__ out,
                                                     int K, int N, int Kp) {
  __shared__ float tile[64][65];
  int kt = blockIdx.x * 64, nt = blockIdx.y * 64;
  int c = threadIdx.x & 63, r0 = threadIdx.x >> 6;
  for (int rr = 0; rr < 64; rr += 4) {
    int k = kt + rr + r0;
    tile[rr + r0][c] = (k < K) ? in[(size_t)k * N + nt + c] : 0.f;
  }
  __syncthreads();
  for (int rr = 0; rr < 64; rr += 4) {
    int n = nt + rr + r0;
    out[(size_t)n * Kp + kt + c] = f2bf(tile[c][rr + r0]);
  }
}

// W_h [512][2048] fp32 -> MFMA B-fragment order, split hi/lo bf16.
// layout: [gw=g*4+w][s(kstep 0..31)][lane(64)][8];  element = W_h[s*16+(lane>>5)*8+j][w*512+g*32+(lane&31)]
__global__ __launch_bounds__(256) void prep_whfrag(const float* __restrict__ Wh,
                                                   u16* __restrict__ hi, u16* __restrict__ lo) {
  int gid = blockIdx.x * 256 + threadIdx.x;    // [0, 131072)
  int l = gid & 63, s = (gid >> 6) & 31, gw = gid >> 11;
  int g = gw >> 2, w = gw & 3;
  int kin  = s * 16 + ((l >> 5) << 3);
  int jcol = w * 512 + g * 32 + (l & 31);
  u16* ph = hi + (size_t)gid * 8;
  u16* pl = lo + (size_t)gid * 8;
#pragma unroll
  for (int i = 0; i < 8; i++) {
    float v = Wh[(size_t)(kin + i) * 2048 + jcol];
    u16 h = f2bf(v);
    ph[i] = h;
    pl[i] = f2bf(v - bf2f(h));
  }
}

// h0 -> fragment-order hi/lo into hx slot 0
__global__ __launch_bounds__(256) void prep_hinit(const float* __restrict__ h0,
                                                  u16* __restrict__ hx_hi, u16* __restrict__ hx_lo) {
  int idx = blockIdx.x * 256 + threadIdx.x;    // 16384
  int b = idx >> 9, k = idx & 511;
  float v = h0[idx];
  u16 h = f2bf(v);
  int chunk = (k >> 4) * 64 + b * 2 + ((k >> 3) & 1);
  int pos = chunk * 8 + (k & 7);
  hx_hi[pos] = h;
  hx_lo[pos] = f2bf(v - bf2f(h));
}

// ---------- GEMM: C[M][ldc] = A[M][lda](bf16) * Bt[N][ldb](bf16)^T + bias[n] ----------
// 128x128 tile, BK=64, 4 waves (2x2 of 64x64), 16x16x32 MFMA, global_load_lds staging.
__global__ __launch_bounds__(256, 2) void gemm_bt(const u16* __restrict__ A, int lda,
                                                  const u16* __restrict__ Bt, int ldb,
                                                  float* __restrict__ C, int ldc,
                                                  const float* __restrict__ bias, int K) {
  __shared__ u16 As[8192];
  __shared__ u16 Bs[8192];
  const int tid = threadIdx.x, lane = tid & 63, wave = tid >> 6;
  const int m0 = blockIdx.y * 128, n0 = blockIdx.x * 128;
  const int wm = (wave >> 1) * 64, wn = (wave & 1) * 64;
  f32x4 acc[4][4];
#pragma unroll
  for (int i = 0; i < 4; i++)
#pragma unroll
    for (int j = 0; j < 4; j++)
#pragma unroll
      for (int r = 0; r < 4; r++) acc[i][j][r] = 0.f;

  const int qbase = wave * 4 * 64 + lane;
  for (int k0 = 0; k0 < K; k0 += 64) {
    __syncthreads();
#pragma unroll
    for (int ii = 0; ii < 4; ii++) {
      int q = qbase + ii * 64;
      int mm = q & 127, kb = q >> 7;
      gl_lds16(A  + (size_t)(m0 + mm) * lda + k0 + kb * 8, As + (size_t)(wave * 4 + ii) * 512);
      gl_lds16(Bt + (size_t)(n0 + mm) * ldb + k0 + kb * 8, Bs + (size_t)(wave * 4 + ii) * 512);
    }
    __syncthreads();
#pragma unroll
    for (int kk = 0; kk < 2; kk++) {
      const int kb  = kk * 4 + (lane >> 4);
      const int row = lane & 15;
      bf16x8 af[4], bfr[4];
#pragma unroll
      for (int s = 0; s < 4; s++) {
        af[s]  = *(const bf16x8*)(As + (size_t)(kb * 128 + wm + s * 16 + row) * 8);
        bfr[s] = *(const bf16x8*)(Bs + (size_t)(kb * 128 + wn + s * 16 + row) * 8);
      }
#pragma unroll
      for (int i = 0; i < 4; i++)
#pragma unroll
        for (int j = 0; j < 4; j++)
          acc[i][j] = mfma16(af[i], bfr[j], acc[i][j]);
    }
  }
  const int coln = lane & 15, rquad = lane >> 4;
#pragma unroll
  for (int j = 0; j < 4; j++) {
    int n = n0 + wn + j * 16 + coln;
    float bv = bias[n];
#pragma unroll
    for (int i = 0; i < 4; i++) {
      int mb = m0 + wm + i * 16 + rquad * 4;
#pragma unroll
      for (int r = 0; r < 4; r++)
        C[(size_t)(mb + r) * ldc + n] = acc[i][j][r] + bv;
    }
  }
}

// ---------- persistent LSTM recurrence ----------
// 16 WGs x 256 thr. WG g owns hidden cols [g*32, g*32+32); wave w computes gate w's
// z-tile [32b x 32k] via 32x32x16 MFMA (split-bf16, 3 independent acc chains).
// h-state exchange is device-COHERENT (relaxed agent atomics, sc0/sc1 write-through /
// L2-bypass loads) through fragment-ordered ping-pong buffers -> NO __threadfence,
// NO buffer_inv, so the per-WG W_h slice stays resident in its XCD L2 all 128 steps.
// Barrier: lane0 of each wave does a RELEASE fetch_add (wave-level release orders that
// wave's vmcnt-tracked h stores); last arriver sets flag; tid0 polls relaxed.
__global__ __launch_bounds__(256, 1) void lstm_rec(
    const float* __restrict__ xz, const float* __restrict__ cell_in,
    u16* __restrict__ hx_hi, u16* __restrict__ hx_lo, u16* __restrict__ hs,
    const u16* __restrict__ whhi, const u16* __restrict__ whlo,
    float* __restrict__ out_h, float* __restrict__ out_c, int* bar) {
  __shared__ __align__(16) u16 Ah[16384];      // 32 KB  h_hi fragment-order
  __shared__ __align__(16) u16 Al[16384];      // 32 KB  h_lo fragment-order
  __shared__ float zb[4][32][32];              // 16 KB
  __shared__ float ctile[1024];                // 4 KB
  const int tid = threadIdx.x, lane = tid & 63, wave = tid >> 6;
  const int g = blockIdx.x;
  for (int p = tid; p < 1024; p += 256) {
    int b = p >> 5, ko = p & 31;
    ctile[p] = cell_in[b * 512 + g * 32 + ko];
  }
  const int jcol = wave * 512 + g * 32 + (lane & 31);
  const u16* bhib = whhi + (size_t)(g * 4 + wave) * 16384 + lane * 8;
  const u16* blob = whlo + (size_t)(g * 4 + wave) * 16384 + lane * 8;
  const int lchunk = (lane & 31) * 2 + (lane >> 5);  // A-frag 16B-chunk within a kstep
  int brow[16];                                 // C/D row map: (reg&3)+8*(reg>>2)+4*(lane>>5)
#pragma unroll
  for (int r = 0; r < 16; r++) brow[r] = 4 * (lane >> 5) + (r & 3) + 8 * (r >> 2);
  float xzr[16];
#pragma unroll
  for (int r = 0; r < 16; r++) xzr[r] = xz[(size_t)(brow[r] * 128 + 0) * 2048 + jcol];
  // store-phase geometry: this thread emits h for (batch sb, cols sk0..sk0+3)
  const int sb  = tid >> 3;
  const int ko0 = (tid & 7) * 4;
  const int sk0 = g * 32 + ko0;
  const int schunk = (sk0 >> 4) * 64 + sb * 2 + ((sk0 >> 3) & 1);
  const int sull = schunk * 2 + ((sk0 >> 2) & 1);   // ull index within a 4096-ull slot
  ull* hxh = (ull*)hx_hi;
  ull* hxl = (ull*)hx_lo;

  for (int t = 0; t < 128; t++) {
    // ---- stage h(t-1) hi/lo (coherent L2-bypass loads) into LDS, fragment order ----
    const ull* ph = hxh + (size_t)(t & 1) * 4096;
    const ull* pl = hxl + (size_t)(t & 1) * 4096;
    ull vh[16], vl[16];
#pragma unroll
    for (int i = 0; i < 16; i++)
      vh[i] = __hip_atomic_load(ph + i * 256 + tid, __ATOMIC_RELAXED, __HIP_MEMORY_SCOPE_AGENT);
#pragma unroll
    for (int i = 0; i < 16; i++)
      vl[i] = __hip_atomic_load(pl + i * 256 + tid, __ATOMIC_RELAXED, __HIP_MEMORY_SCOPE_AGENT);
#pragma unroll
    for (int i = 0; i < 16; i++) ((ull*)Ah)[i * 256 + tid] = vh[i];
#pragma unroll
    for (int i = 0; i < 16; i++) ((ull*)Al)[i * 256 + tid] = vl[i];
    __syncthreads();

    f32x16 acc0, acc1, acc2;
#pragma unroll
    for (int r = 0; r < 16; r++) { acc0[r] = xzr[r]; acc1[r] = 0.f; acc2[r] = 0.f; }
    if (t < 127) {                              // prefetch next step's xz (no dep on barrier)
#pragma unroll
      for (int r = 0; r < 16; r++) xzr[r] = xz[(size_t)(brow[r] * 128 + t + 1) * 2048 + jcol];
    }
#pragma unroll 8
    for (int s = 0; s < 32; s++) {
      bf16x8 a_hi = *(const bf16x8*)(Ah + s * 512 + lchunk * 8);     // conflict-free b128
      bf16x8 a_lo = *(const bf16x8*)(Al + s * 512 + lchunk * 8);
      bf16x8 b_hi = *(const bf16x8*)(bhib + (size_t)s * 512);        // L2-resident weights
      bf16x8 b_lo = *(const bf16x8*)(blob + (size_t)s * 512);
      acc0 = mfma32(a_hi, b_hi, acc0);          // 3 independent chains hide MFMA latency
      acc1 = mfma32(a_hi, b_lo, acc1);
      acc2 = mfma32(a_lo, b_hi, acc2);
    }
#pragma unroll
    for (int r = 0; r < 16; r++)
      zb[wave][brow[r]][lane & 31] = acc0[r] + acc1[r] + acc2[r];
    __syncthreads();

    // ---- gate combine: 4 consecutive cols per thread -> packed 8B coherent stores ----
    u16 hh[4], hl[4];
    float hv[4], cv[4];
#pragma unroll
    for (int q = 0; q < 4; q++) {
      int ko = ko0 + q, p = sb * 32 + ko;
      float zi = zb[0][sb][ko], zf_ = zb[1][sb][ko], zg = zb[2][sb][ko], zo = zb[3][sb][ko];
      float c = sigf(zf_) * ctile[p] + sigf(zi) * tanh_(zg);
      float h = sigf(zo) * tanh_(c);
      ctile[p] = c;
      hh[q] = f2bf(h);
      hl[q] = f2bf(h - bf2f(hh[q]));
      hv[q] = h; cv[q] = c;
    }
    ull packh = (ull)hh[0] | ((ull)hh[1] << 16) | ((ull)hh[2] << 32) | ((ull)hh[3] << 48);
    ull packl = (ull)hl[0] | ((ull)hl[1] << 16) | ((ull)hl[2] << 32) | ((ull)hl[3] << 48);
    const size_t wbase = (size_t)((t + 1) & 1) * 4096;
    __hip_atomic_store(hxh + wbase + sull, packh, __ATOMIC_RELAXED, __HIP_MEMORY_SCOPE_AGENT);
    __hip_atomic_store(hxl + wbase + sull, packl, __ATOMIC_RELAXED, __HIP_MEMORY_SCOPE_AGENT);
    __hip_atomic_store((ull*)(hs + (size_t)(sb * 128 + t) * 512 + sk0), packh,
                       __ATOMIC_RELAXED, __HIP_MEMORY_SCOPE_AGENT);  // row-major copy for GEMM
    if (t == 127) {
#pragma unroll
      for (int q = 0; q < 4; q++) {
        out_h[sb * 512 + sk0 + q] = hv[q];
        out_c[sb * 512 + sk0 + q] = cv[q];
      }
    }
    // ---- grid barrier (no cache invalidation) ----
    if (lane == 0) {                            // per-wave RELEASE orders this wave's stores
      int prev = __hip_atomic_fetch_add(bar, 1, __ATOMIC_RELEASE, __HIP_MEMORY_SCOPE_AGENT);
      if (prev == 64 * (t + 1) - 1)
        __hip_atomic_store(bar + 16, t + 1, __ATOMIC_RELEASE, __HIP_MEMORY_SCOPE_AGENT);
    }
    if (tid == 0) {
      while (__hip_atomic_load(bar + 16, __ATOMIC_RELAXED, __HIP_MEMORY_SCOPE_AGENT) < t + 1)
        __builtin_amdgcn_s_sleep(1);
    }
    __syncthreads();
  }
}

// ---------- launch ----------
extern "C" void kernel_launch(void* const* d_in, const int* in_sizes, int n_in,
                              void* d_out, int out_size, void* d_ws, size_t ws_size,
                              hipStream_t stream) {
  const int*   toks = (const int*)d_in[0];
  const float* hid0 = (const float*)d_in[1];
  const float* cel0 = (const float*)d_in[2];
  const float* emb  = (const float*)d_in[3];
  const float* Wx   = (const float*)d_in[4];
  const float* Wh   = (const float*)d_in[5];
  const float* bg   = (const float*)d_in[6];
  const float* Wout = (const float*)d_in[7];
  const float* bout = (const float*)d_in[8];
  float* out = (float*)d_out;
  char* ws = (char*)d_ws;

  float* xz  = (float*)(ws + OFF_XZ);
  u16* aemb  = (u16*)(ws + OFF_AEMB);
  u16* wxT   = (u16*)(ws + OFF_WXT);
  u16* woT   = (u16*)(ws + OFF_WOT);
  u16* whhi  = (u16*)(ws + OFF_WHHI);
  u16* whlo  = (u16*)(ws + OFF_WHLO);
  u16* hs    = (u16*)(ws + OFF_HS);
  u16* hxhi  = (u16*)(ws + OFF_HXHI);
  u16* hxlo  = (u16*)(ws + OFF_HXLO);
  int* bar   = (int*)(ws + OFF_BAR);

  hipMemsetAsync(bar, 0, 256, stream);
  prep_aemb<<<4096, 256, 0, stream>>>(toks, emb, aemb);
  transpose_cvt<<<dim3(5, 32), 256, 0, stream>>>(Wx, wxT, 300, 2048, 320);
  transpose_cvt<<<dim3(8, 500), 256, 0, stream>>>(Wout, woT, 512, 32000, 512);
  prep_whfrag<<<512, 256, 0, stream>>>(Wh, whhi, whlo);
  prep_hinit<<<64, 256, 0, stream>>>(hid0, hxhi, hxlo);
  // xz = embed @ W_x + b   (M=4096, N=2048, K=320)
  gemm_bt<<<dim3(16, 32), 256, 0, stream>>>(aemb, 320, wxT, 320, xz, 2048, bg, 320);
  // 128-step LSTM scan (persistent, 16 WGs, coherent h-exchange, 1 grid barrier/step)
  lstm_rec<<<16, 256, 0, stream>>>(xz, cel0, hxhi, hxlo, hs, whhi, whlo,
                                   out + 131072000, out + 131072000 + 16384, bar);
  // logits = hs @ W_out + b_out   (M=4096, N=32000, K=512)
  gemm_bt<<<dim3(250, 32), 256, 0, stream>>>(hs, 512, woT, 512, out, 32000, bout, 512);
}

// Round 3
// 1580.930 us; speedup vs baseline: 1.8516x; 1.1794x over previous
//
#include <hip/hip_runtime.h>
#include <cstdint>

using u16 = unsigned short;
using ull = unsigned long long;
typedef __bf16 bf16x8 __attribute__((ext_vector_type(8)));
typedef float  f32x4  __attribute__((ext_vector_type(4)));
typedef float  f32x16 __attribute__((ext_vector_type(16)));

#define DEV __device__ __forceinline__

// ---------- constants ----------
// B=32, T=128, V=32000, E=300(->320), H=512, 4H=2048, M=B*T=4096
static constexpr size_t OFF_XZ    = 0;                       // 4096*2048*4   = 33554432
static constexpr size_t OFF_AEMB  = 33554432;                // 4096*320*2    = 2621440
static constexpr size_t OFF_WXT   = 36175872;                // 2048*320*2    = 1310720
static constexpr size_t OFF_WOT   = 37486592;                // 32000*512*2   = 32768000
static constexpr size_t OFF_WHHI  = 70254592;                // 64*32*64*8*2  = 2097152
static constexpr size_t OFF_WHLO  = 72351744;                // 2097152
static constexpr size_t OFF_HS    = 74448896;                // 4096*512*2    = 4194304
static constexpr size_t OFF_HXHI  = 78643200;                // 2 slots * 32*512*2 = 65536
static constexpr size_t OFF_HXLO  = 78708736;                // 65536
static constexpr size_t OFF_BAR   = 78774272;                // 4096 bytes (16 slots, 128B apart)

// ---------- helpers ----------
DEV u16 f2bf(float x) {                       // round-to-nearest-even fp32 -> bf16 bits
  union { float f; uint32_t u; } v; v.f = x;
  uint32_t r = v.u + 0x7fffu + ((v.u >> 16) & 1u);
  return (u16)(r >> 16);
}
DEV float bf2f(u16 h) { union { uint32_t u; float f; } v; v.u = ((uint32_t)h) << 16; return v.f; }
DEV float sigf(float x)  { return 1.f / (1.f + __expf(-x)); }
DEV float tanh_(float x) { return 2.f / (1.f + __expf(-2.f * x)) - 1.f; }

DEV f32x4 mfma16(bf16x8 a, bf16x8 b, f32x4 c) {
  return __builtin_amdgcn_mfma_f32_16x16x32_bf16(a, b, c, 0, 0, 0);
}
DEV f32x16 mfma32(bf16x8 a, bf16x8 b, f32x16 c) {
  return __builtin_amdgcn_mfma_f32_32x32x16_bf16(a, b, c, 0, 0, 0);
}
DEV void gl_lds16(const u16* g, u16* l) {     // async global->LDS, 16B/lane, dest = base + lane*16
  __builtin_amdgcn_global_load_lds(
      (const __attribute__((address_space(1))) uint32_t*)g,
      (__attribute__((address_space(3))) uint32_t*)l, 16, 0, 0);
}

// Fragment-order position of h element (b, k) within a 16384-u16 slot:
//   chunk16B = (k>>4)*64 + b*2 + ((k>>3)&1), elem j = k&7
// MFMA A-frag read for lane: chunk = s*64 + (lane&31)*2 + (lane>>5) -> 64 consecutive
// 16B chunks per wave-read = conflict-free ds_read_b128.

// ---------- prep kernels ----------
__global__ __launch_bounds__(256) void prep_aemb(const int* __restrict__ toks,
                                                 const float* __restrict__ emb,
                                                 u16* __restrict__ A) {
  int m = blockIdx.x;                          // row = b*T + t
  int tok = toks[m];
  const float* src = emb + (size_t)tok * 300;
  for (int k = threadIdx.x; k < 320; k += 256)
    A[(size_t)m * 320 + k] = (k < 300) ? f2bf(src[k]) : (u16)0;
}

// out[n][k] = (bf16) in[k][n];  K rows in, Kp (padded, %64) cols out, N %64
__global__ __launch_bounds__(256) void transpose_cvt(const float* __restrict__ in,
                                                     u16* __restrict__ out,
                                                     int K, int N, int Kp) {
  __shared__ float tile[64][65];
  int kt = blockIdx.x * 64, nt = blockIdx.y * 64;
  int c = threadIdx.x & 63, r0 = threadIdx.x >> 6;
  for (int rr = 0; rr < 64; rr += 4) {
    int k = kt + rr + r0;
    tile[rr + r0][c] = (k < K) ? in[(size_t)k * N + nt + c] : 0.f;
  }
  __syncthreads();
  for (int rr = 0; rr < 64; rr += 4) {
    int n = nt + rr + r0;
    out[(size_t)n * Kp + kt + c] = f2bf(tile[c][rr + r0]);
  }
}

// W_h [512][2048] fp32 -> MFMA B-fragment order, split hi/lo bf16.
// layout: [gw=g*4+w][s(kstep 0..31)][lane(64)][8];  element = W_h[s*16+(lane>>5)*8+j][w*512+g*32+(lane&31)]
__global__ __launch_bounds__(256) void prep_whfrag(const float* __restrict__ Wh,
                                                   u16* __restrict__ hi, u16* __restrict__ lo) {
  int gid = blockIdx.x * 256 + threadIdx.x;    // [0, 131072)
  int l = gid & 63, s = (gid >> 6) & 31, gw = gid >> 11;
  int g = gw >> 2, w = gw & 3;
  int kin  = s * 16 + ((l >> 5) << 3);
  int jcol = w * 512 + g * 32 + (l & 31);
  u16* ph = hi + (size_t)gid * 8;
  u16* pl = lo + (size_t)gid * 8;
#pragma unroll
  for (int i = 0; i < 8; i++) {
    float v = Wh[(size_t)(kin + i) * 2048 + jcol];
    u16 h = f2bf(v);
    ph[i] = h;
    pl[i] = f2bf(v - bf2f(h));
  }
}

// h0 -> fragment-order hi/lo into hx slot 0
__global__ __launch_bounds__(256) void prep_hinit(const float* __restrict__ h0,
                                                  u16* __restrict__ hx_hi, u16* __restrict__ hx_lo) {
  int idx = blockIdx.x * 256 + threadIdx.x;    // 16384
  int b = idx >> 9, k = idx & 511;
  float v = h0[idx];
  u16 h = f2bf(v);
  int chunk = (k >> 4) * 64 + b * 2 + ((k >> 3) & 1);
  int pos = chunk * 8 + (k & 7);
  hx_hi[pos] = h;
  hx_lo[pos] = f2bf(v - bf2f(h));
}

// ---------- GEMM: C[M][ldc] = A[M][lda](bf16) * Bt[N][ldb](bf16)^T + bias[n] ----------
// 128x128 tile, BK=64, 4 waves (2x2 of 64x64), 16x16x32 MFMA, global_load_lds staging.
__global__ __launch_bounds__(256, 2) void gemm_bt(const u16* __restrict__ A, int lda,
                                                  const u16* __restrict__ Bt, int ldb,
                                                  float* __restrict__ C, int ldc,
                                                  const float* __restrict__ bias, int K) {
  __shared__ u16 As[8192];
  __shared__ u16 Bs[8192];
  const int tid = threadIdx.x, lane = tid & 63, wave = tid >> 6;
  const int m0 = blockIdx.y * 128, n0 = blockIdx.x * 128;
  const int wm = (wave >> 1) * 64, wn = (wave & 1) * 64;
  f32x4 acc[4][4];
#pragma unroll
  for (int i = 0; i < 4; i++)
#pragma unroll
    for (int j = 0; j < 4; j++)
#pragma unroll
      for (int r = 0; r < 4; r++) acc[i][j][r] = 0.f;

  const int qbase = wave * 4 * 64 + lane;
  for (int k0 = 0; k0 < K; k0 += 64) {
    __syncthreads();
#pragma unroll
    for (int ii = 0; ii < 4; ii++) {
      int q = qbase + ii * 64;
      int mm = q & 127, kb = q >> 7;
      gl_lds16(A  + (size_t)(m0 + mm) * lda + k0 + kb * 8, As + (size_t)(wave * 4 + ii) * 512);
      gl_lds16(Bt + (size_t)(n0 + mm) * ldb + k0 + kb * 8, Bs + (size_t)(wave * 4 + ii) * 512);
    }
    __syncthreads();
#pragma unroll
    for (int kk = 0; kk < 2; kk++) {
      const int kb  = kk * 4 + (lane >> 4);
      const int row = lane & 15;
      bf16x8 af[4], bfr[4];
#pragma unroll
      for (int s = 0; s < 4; s++) {
        af[s]  = *(const bf16x8*)(As + (size_t)(kb * 128 + wm + s * 16 + row) * 8);
        bfr[s] = *(const bf16x8*)(Bs + (size_t)(kb * 128 + wn + s * 16 + row) * 8);
      }
#pragma unroll
      for (int i = 0; i < 4; i++)
#pragma unroll
        for (int j = 0; j < 4; j++)
          acc[i][j] = mfma16(af[i], bfr[j], acc[i][j]);
    }
  }
  const int coln = lane & 15, rquad = lane >> 4;
#pragma unroll
  for (int j = 0; j < 4; j++) {
    int n = n0 + wn + j * 16 + coln;
    float bv = bias[n];
#pragma unroll
    for (int i = 0; i < 4; i++) {
      int mb = m0 + wm + i * 16 + rquad * 4;
#pragma unroll
      for (int r = 0; r < 4; r++)
        C[(size_t)(mb + r) * ldc + n] = acc[i][j][r] + bv;
    }
  }
}

// ---------- persistent LSTM recurrence ----------
// 16 WGs x 256 thr. WG g owns hidden cols [g*32, g*32+32); wave w computes gate w's
// z-tile [32b x 32k] via 32x32x16 MFMA (split-bf16, 3 independent acc chains).
// W_h fragments (64 x bf16x8 = 256 VGPRs) live in REGISTERS for all 128 steps.
// h-state exchange is device-COHERENT (relaxed agent atomics = write-through
// stores / L2-bypass loads) through fragment-ordered ping-pong buffers ->
// NO __threadfence, NO buffer_inv, W_h source stays L2-resident.
// Barrier: __syncthreads drains vmcnt(0) (agent-atomic stores then sit at the
// coherence point) -> tid0 RELEASE-stores its own 128B-spaced slot (no RMW
// serialization) -> wave0 lanes 0..15 each poll one slot (divergent spin;
// exec-mask reconvergence is the all-reduce).
__global__ __launch_bounds__(256, 1) void lstm_rec(
    const float* __restrict__ xz, const float* __restrict__ cell_in,
    u16* __restrict__ hx_hi, u16* __restrict__ hx_lo, u16* __restrict__ hs,
    const u16* __restrict__ whhi, const u16* __restrict__ whlo,
    float* __restrict__ out_h, float* __restrict__ out_c, int* bar) {
  __shared__ __align__(16) u16 Ah[16384];      // 32 KB  h_hi fragment-order
  __shared__ __align__(16) u16 Al[16384];      // 32 KB  h_lo fragment-order
  __shared__ float zb[4][32][32];              // 16 KB
  __shared__ float ctile[1024];                // 4 KB
  const int tid = threadIdx.x, lane = tid & 63, wave = tid >> 6;
  const int g = blockIdx.x;
  for (int p = tid; p < 1024; p += 256) {
    int b = p >> 5, ko = p & 31;
    ctile[p] = cell_in[b * 512 + g * 32 + ko];
  }
  const int jcol = wave * 512 + g * 32 + (lane & 31);
  const u16* bhib = whhi + (size_t)(g * 4 + wave) * 16384 + lane * 8;
  const u16* blob = whlo + (size_t)(g * 4 + wave) * 16384 + lane * 8;
  // ---- W_h fragments -> registers (256 VGPRs), resident for the whole scan ----
  bf16x8 Bh[32], Bl[32];
#pragma unroll
  for (int s = 0; s < 32; s++) {
    Bh[s] = *(const bf16x8*)(bhib + (size_t)s * 512);
    Bl[s] = *(const bf16x8*)(blob + (size_t)s * 512);
  }
  const int lchunk = (lane & 31) * 2 + (lane >> 5);  // A-frag 16B-chunk within a kstep
  int brow[16];                                 // C/D row map: (reg&3)+8*(reg>>2)+4*(lane>>5)
#pragma unroll
  for (int r = 0; r < 16; r++) brow[r] = 4 * (lane >> 5) + (r & 3) + 8 * (r >> 2);
  float xzr[16];
#pragma unroll
  for (int r = 0; r < 16; r++) xzr[r] = xz[(size_t)(brow[r] * 128 + 0) * 2048 + jcol];
  // store-phase geometry: this thread emits h for (batch sb, cols sk0..sk0+3)
  const int sb  = tid >> 3;
  const int ko0 = (tid & 7) * 4;
  const int sk0 = g * 32 + ko0;
  const int schunk = (sk0 >> 4) * 64 + sb * 2 + ((sk0 >> 3) & 1);
  const int sull = schunk * 2 + ((sk0 >> 2) & 1);   // ull index within a 4096-ull slot
  ull* hxh = (ull*)hx_hi;
  ull* hxl = (ull*)hx_lo;

  for (int t = 0; t < 128; t++) {
    // ---- stage h(t-1) hi/lo (coherent L2-bypass loads) into LDS, fragment order ----
    const ull* ph = hxh + (size_t)(t & 1) * 4096;
    const ull* pl = hxl + (size_t)(t & 1) * 4096;
    ull vh[16], vl[16];
#pragma unroll
    for (int i = 0; i < 16; i++)
      vh[i] = __hip_atomic_load(ph + i * 256 + tid, __ATOMIC_RELAXED, __HIP_MEMORY_SCOPE_AGENT);
#pragma unroll
    for (int i = 0; i < 16; i++)
      vl[i] = __hip_atomic_load(pl + i * 256 + tid, __ATOMIC_RELAXED, __HIP_MEMORY_SCOPE_AGENT);
#pragma unroll
    for (int i = 0; i < 16; i++) ((ull*)Ah)[i * 256 + tid] = vh[i];
#pragma unroll
    for (int i = 0; i < 16; i++) ((ull*)Al)[i * 256 + tid] = vl[i];
    __syncthreads();

    f32x16 acc0, acc1, acc2;
#pragma unroll
    for (int r = 0; r < 16; r++) { acc0[r] = xzr[r]; acc1[r] = 0.f; acc2[r] = 0.f; }
    if (t < 127) {                              // prefetch next step's xz (no dep on barrier)
#pragma unroll
      for (int r = 0; r < 16; r++) xzr[r] = xz[(size_t)(brow[r] * 128 + t + 1) * 2048 + jcol];
    }
#pragma unroll
    for (int s = 0; s < 32; s++) {
      bf16x8 a_hi = *(const bf16x8*)(Ah + s * 512 + lchunk * 8);     // conflict-free b128
      bf16x8 a_lo = *(const bf16x8*)(Al + s * 512 + lchunk * 8);
      acc0 = mfma32(a_hi, Bh[s], acc0);         // 3 independent chains hide MFMA latency
      acc1 = mfma32(a_hi, Bl[s], acc1);
      acc2 = mfma32(a_lo, Bh[s], acc2);
    }
#pragma unroll
    for (int r = 0; r < 16; r++)
      zb[wave][brow[r]][lane & 31] = acc0[r] + acc1[r] + acc2[r];
    __syncthreads();

    // ---- gate combine: 4 consecutive cols per thread -> packed 8B coherent stores ----
    u16 hh[4], hl[4];
    float hv[4], cv[4];
#pragma unroll
    for (int q = 0; q < 4; q++) {
      int ko = ko0 + q, p = sb * 32 + ko;
      float zi = zb[0][sb][ko], zf_ = zb[1][sb][ko], zg = zb[2][sb][ko], zo = zb[3][sb][ko];
      float c = sigf(zf_) * ctile[p] + sigf(zi) * tanh_(zg);
      float h = sigf(zo) * tanh_(c);
      ctile[p] = c;
      hh[q] = f2bf(h);
      hl[q] = f2bf(h - bf2f(hh[q]));
      hv[q] = h; cv[q] = c;
    }
    ull packh = (ull)hh[0] | ((ull)hh[1] << 16) | ((ull)hh[2] << 32) | ((ull)hh[3] << 48);
    ull packl = (ull)hl[0] | ((ull)hl[1] << 16) | ((ull)hl[2] << 32) | ((ull)hl[3] << 48);
    const size_t wbase = (size_t)((t + 1) & 1) * 4096;
    __hip_atomic_store(hxh + wbase + sull, packh, __ATOMIC_RELAXED, __HIP_MEMORY_SCOPE_AGENT);
    __hip_atomic_store(hxl + wbase + sull, packl, __ATOMIC_RELAXED, __HIP_MEMORY_SCOPE_AGENT);
    __hip_atomic_store((ull*)(hs + (size_t)(sb * 128 + t) * 512 + sk0), packh,
                       __ATOMIC_RELAXED, __HIP_MEMORY_SCOPE_AGENT);  // row-major copy for GEMM
    if (t == 127) {
#pragma unroll
      for (int q = 0; q < 4; q++) {
        out_h[sb * 512 + sk0 + q] = hv[q];
        out_c[sb * 512 + sk0 + q] = cv[q];
      }
    }
    // ---- grid barrier: slot store + parallel poll (no RMW serialization) ----
    __syncthreads();                            // drains vmcnt(0): all WG stores coherent-visible
    if (tid == 0)
      __hip_atomic_store(bar + g * 32, t + 1, __ATOMIC_RELEASE, __HIP_MEMORY_SCOPE_AGENT);
    if (wave == 0 && lane < 16) {
      while (__hip_atomic_load(bar + lane * 32, __ATOMIC_RELAXED, __HIP_MEMORY_SCOPE_AGENT) < t + 1)
        __builtin_amdgcn_s_sleep(1);
    }
    __syncthreads();
  }
}

// ---------- launch ----------
extern "C" void kernel_launch(void* const* d_in, const int* in_sizes, int n_in,
                              void* d_out, int out_size, void* d_ws, size_t ws_size,
                              hipStream_t stream) {
  const int*   toks = (const int*)d_in[0];
  const float* hid0 = (const float*)d_in[1];
  const float* cel0 = (const float*)d_in[2];
  const float* emb  = (const float*)d_in[3];
  const float* Wx   = (const float*)d_in[4];
  const float* Wh   = (const float*)d_in[5];
  const float* bg   = (const float*)d_in[6];
  const float* Wout = (const float*)d_in[7];
  const float* bout = (const float*)d_in[8];
  float* out = (float*)d_out;
  char* ws = (char*)d_ws;

  float* xz  = (float*)(ws + OFF_XZ);
  u16* aemb  = (u16*)(ws + OFF_AEMB);
  u16* wxT   = (u16*)(ws + OFF_WXT);
  u16* woT   = (u16*)(ws + OFF_WOT);
  u16* whhi  = (u16*)(ws + OFF_WHHI);
  u16* whlo  = (u16*)(ws + OFF_WHLO);
  u16* hs    = (u16*)(ws + OFF_HS);
  u16* hxhi  = (u16*)(ws + OFF_HXHI);
  u16* hxlo  = (u16*)(ws + OFF_HXLO);
  int* bar   = (int*)(ws + OFF_BAR);

  hipMemsetAsync(bar, 0, 4096, stream);
  prep_aemb<<<4096, 256, 0, stream>>>(toks, emb, aemb);
  transpose_cvt<<<dim3(5, 32), 256, 0, stream>>>(Wx, wxT, 300, 2048, 320);
  transpose_cvt<<<dim3(8, 500), 256, 0, stream>>>(Wout, woT, 512, 32000, 512);
  prep_whfrag<<<512, 256, 0, stream>>>(Wh, whhi, whlo);
  prep_hinit<<<64, 256, 0, stream>>>(hid0, hxhi, hxlo);
  // xz = embed @ W_x + b   (M=4096, N=2048, K=320)
  gemm_bt<<<dim3(16, 32), 256, 0, stream>>>(aemb, 320, wxT, 320, xz, 2048, bg, 320);
  // 128-step LSTM scan (persistent, 16 WGs, coherent h-exchange, slot barrier)
  lstm_rec<<<16, 256, 0, stream>>>(xz, cel0, hxhi, hxlo, hs, whhi, whlo,
                                   out + 131072000, out + 131072000 + 16384, bar);
  // logits = hs @ W_out + b_out   (M=4096, N=32000, K=512)
  gemm_bt<<<dim3(250, 32), 256, 0, stream>>>(hs, 512, woT, 512, out, 32000, bout, 512);
}